// Round 9
// baseline (613.165 us; speedup 1.0000x reference)
//
#include <hip/hip_runtime.h>
#include <hip/hip_bf16.h>

// ACLSTM on MI355X — persistent-RNN, time-chunked + software-pipelined.
// R9: CU-exclusive k2. Single change vs R8-PASS: mega smem = 80 KB so every
//     block (k2/k1/k3) is alone on its CU. k2's serial loop gets clean MFMA/
//     VALU pipes (R8 analysis: ~1280cy/SIMD/step MFMA floor + ~680cy gate
//     math, observed 2830cy -> ~1000cy suspected k1-contention). k1/k3 have
//     ~15x slack on the other 192 CUs. Bodies byte-identical to R8.

typedef float f32x4 __attribute__((ext_vector_type(4)));
typedef int   i32x4 __attribute__((ext_vector_type(4)));
typedef short s16x8 __attribute__((ext_vector_type(8)));
typedef short s16x4 __attribute__((ext_vector_type(4)));
typedef unsigned short u16x4 __attribute__((ext_vector_type(4)));

#define L2E   1.44269504088896340736f
#define L2E2  2.88539008177792681472f

__device__ __forceinline__ float fexp2(float x) {
#if __has_builtin(__builtin_amdgcn_exp2f)
  return __builtin_amdgcn_exp2f(x);
#else
  float r; asm("v_exp_f32 %0, %1" : "=v"(r) : "v"(x)); return r;
#endif
}
__device__ __forceinline__ float frcp(float x) { return __builtin_amdgcn_rcpf(x); }
__device__ __forceinline__ float bf2f(unsigned short u) {
  return __uint_as_float(((unsigned)u) << 16);
}
__device__ __forceinline__ unsigned short f2bf(float f) {   // RNE f32->bf16
  unsigned int b = __float_as_uint(f);
  return (unsigned short)((b + 0x7FFFu + ((b >> 16) & 1u)) >> 16);
}

// ---------------------------------------------------------------- K0: quant
__global__ void k0_quant(const float* __restrict__ Whh,
                         const float* __restrict__ Wlog,
                         const float* __restrict__ Wval,
                         signed char* __restrict__ Wq, float* __restrict__ wsc,
                         signed char* __restrict__ Wlq, float* __restrict__ lsc) {
  int r = blockIdx.x, l = threadIdx.x;   // 1057 rows, 64 lanes
  const float* src; signed char* dst; float* sd;
  if (r < 1024) { src = Whh + (size_t)r * 256; dst = Wq + (size_t)r * 256; sd = wsc + r; }
  else {
    int hr = r - 1024;
    src = (hr < 32) ? (Wlog + (size_t)hr * 256) : Wval;
    dst = Wlq + (size_t)hr * 256; sd = lsc + hr;
  }
  f32x4 v = *(const f32x4*)(src + l * 4);
  float m = fmaxf(fmaxf(fabsf(v.x), fabsf(v.y)), fmaxf(fabsf(v.z), fabsf(v.w)));
  #pragma unroll
  for (int off = 32; off; off >>= 1) m = fmaxf(m, __shfl_xor(m, off));
  float inv = (m > 0.f) ? (127.f / m) : 0.f;
  int q0 = (int)rintf(v.x * inv), q1 = (int)rintf(v.y * inv);
  int q2 = (int)rintf(v.z * inv), q3 = (int)rintf(v.w * inv);
  unsigned int pk = (q0 & 255) | ((q1 & 255) << 8) | ((q2 & 255) << 16) | ((q3 & 255) << 24);
  *(unsigned int*)(dst + l * 4) = pk;
  if (l == 0) *sd = m * (1.f / 127.f);
}

// ================================================================ bodies
// --- K1 body v2 (512 threads): M=128 x N=128(=32j x 4gm), A in regs, B in LDS.
__device__ __forceinline__ void k1_body(int gk, char* smem,
                                        const float* __restrict__ feat,
                                        const float* __restrict__ Wih,
                                        const float* __restrict__ bih,
                                        const float* __restrict__ bhh,
                                        unsigned short* __restrict__ xp, int t0) {
  short (*Bl)[136] = (short (*)[136])smem;                  // 128x136 = 34816 B
  float* bias = (float*)(smem + 34816);                     // 512 B
  const int tid = threadIdx.x;
  const int bm = gk >> 3, bn = gk & 7;
  const int m0 = bm << 7, j0 = bn << 5;
  const int tg = t0 + (bm >> 1), sbase = (bm & 1) << 7;     // 128 | 256
  #pragma unroll
  for (int it = 0; it < 8; ++it) {             // B: 128 g-rows x 128 k
    int idx = it * 512 + tid;
    int rr = idx >> 5, c4 = (idx & 31) << 2;
    int g = ((rr & 3) << 8) + j0 + (rr >> 2);
    f32x4 v = *(const f32x4*)(Wih + (size_t)g * 128 + c4);
    s16x4 pk = { (short)f2bf(v.x), (short)f2bf(v.y), (short)f2bf(v.z), (short)f2bf(v.w) };
    *(s16x4*)&Bl[rr][c4] = pk;
  }
  if (tid < 128) {
    int g = ((tid & 3) << 8) + j0 + (tid >> 2);
    bias[tid] = bih[g] + bhh[g];
  }
  const int w = tid >> 6, l = tid & 63;
  const int lr = l & 15, lk8 = (l >> 4) << 3;
  s16x8 a[4];
  {
    const float* fp = feat + ((size_t)(sbase + (w << 4) + lr) * 512 + tg) * 128 + lk8;
    #pragma unroll
    for (int kk = 0; kk < 4; ++kk) {
      f32x4 v0 = *(const f32x4*)(fp + kk * 32);
      f32x4 v1 = *(const f32x4*)(fp + kk * 32 + 4);
      s16x8 pk = { (short)f2bf(v0.x), (short)f2bf(v0.y), (short)f2bf(v0.z), (short)f2bf(v0.w),
                   (short)f2bf(v1.x), (short)f2bf(v1.y), (short)f2bf(v1.z), (short)f2bf(v1.w) };
      a[kk] = pk;
    }
  }
  __syncthreads();
  f32x4 z = {0.f, 0.f, 0.f, 0.f};
  f32x4 acc[8];
  #pragma unroll
  for (int nt = 0; nt < 8; ++nt) acc[nt] = z;
  #pragma unroll
  for (int kk = 0; kk < 4; ++kk) {
    #pragma unroll
    for (int nt = 0; nt < 8; ++nt) {
      s16x8 bb = *(const s16x8*)&Bl[nt * 16 + lr][kk * 32 + lk8];
      acc[nt] = __builtin_amdgcn_mfma_f32_16x16x32_bf16(a[kk], bb, acc[nt], 0, 0, 0);
    }
  }
  #pragma unroll
  for (int nt = 0; nt < 8; ++nt) {
    #pragma unroll
    for (int r = 0; r < 4; ++r) {
      int m = m0 + (w << 4) + (l >> 4) * 4 + r;   // chunk-local
      int c = nt * 16 + lr;
      float gsc = ((c & 3) == 2) ? L2E2 : -L2E;
      float val = (acc[nt][r] + bias[c]) * gsc;
      xp[(size_t)m * 1024 + (j0 << 2) + c] = f2bf(val);
    }
  }
}

// --- K2 body: 64 blocks x 4 seqs, tc steps, 2 cells/lane.
__device__ __forceinline__ void k2_body(int bid, char* smem,
                                        const unsigned short* __restrict__ xp,
                                        const signed char* __restrict__ Wq,
                                        const float* __restrict__ wsc,
                                        const float* __restrict__ ep,
                                        const float* __restrict__ h0,
                                        const float* __restrict__ c0,
                                        float* __restrict__ hstate,
                                        float* __restrict__ cstate,
                                        signed char* __restrict__ hbuf,
                                        float* __restrict__ out, int t0, int tc) {
  __builtin_amdgcn_s_setprio(3);           // recurrence is the critical path
  signed char (*Hl)[4][272] = (signed char (*)[4][272])smem;  // 2x4x272 = 2176
  float* flgl = (float*)(smem + 2176);     // [lt][4] flags, tc*16 B
  const int tid = threadIdx.x;
  const int w = tid >> 6, l = tid & 63;
  const int lc = l & 15, lq = l >> 4;
  const int hf = lq >> 1;                  // which 16-col half of the wave's 32
  const int odd = lq & 1;                  // which seq pair
  const int sb2 = odd << 1;                // lane's seq base (0 or 2)
  const int j = (w << 5) + (hf << 4) + lc; // lane's h-column
  const int s0 = bid << 2;
  const bool last = (t0 + tc == 512);

  {                                        // stage h rows 0..3 (int8, unmasked)
    const float* hsrc = (t0 == 0) ? h0 : hstate;
    #pragma unroll
    for (int it = 0; it < 2; ++it) {
      int idx = it * 512 + tid;            // 0..1023
      int s = idx >> 8, jj = idx & 255;
      float v = hsrc[(size_t)(s0 + s) * 256 + jj];
      float q = rintf(fminf(fmaxf(v * 127.f, -127.f), 127.f));
      Hl[0][s][jj] = (signed char)(int)q;
    }
  }
  {                                        // stage episode flags [lt][4]
    int n = tc << 2;
    for (int idx = tid; idx < n; idx += 512) {
      int s = idx & 3, llt = idx >> 2;
      flgl[idx] = ep[(size_t)(s0 + s) * 512 + t0 + llt];
    }
  }

  i32x4 wq[8][4];                          // persistent int8 W_hh fragments
  #pragma unroll
  for (int tau = 0; tau < 8; ++tau) {
    int g = (tau >> 1) * 256 + (w << 5) + ((tau & 1) << 4) + lc;
    #pragma unroll
    for (int kk = 0; kk < 4; ++kk)
      wq[tau][kk] = *(const i32x4*)(Wq + (size_t)g * 256 + kk * 64 + (lq << 4));
  }
  float dsc[4];                            // consumer-lane dequant scales
  #pragma unroll
  for (int gamma = 0; gamma < 4; ++gamma) {
    float sgn = (gamma == 2) ? L2E2 : -L2E;
    dsc[gamma] = sgn * wsc[gamma * 256 + j] * (1.f / 127.f);
  }

  float cst[2];                            // c state fp32, seqs s0+sb2+{0,1}
  {
    const float* csrc = (t0 == 0) ? c0 : cstate;
    #pragma unroll
    for (int cc = 0; cc < 2; ++cc)
      cst[cc] = csrc[(size_t)(s0 + sb2 + cc) * 256 + j];
  }

  // xp per-lane elem offset: ((lt*256 + s)*256 + j)*4 ; s = s0+sb2+cc
  const size_t xoff = ((size_t)(s0 + sb2) * 256 + j) * 4;
  u16x4 xqA[2], xqB[2];
  {
    const unsigned short* pp = xp + xoff;  // lt = 0
    #pragma unroll
    for (int cc = 0; cc < 2; ++cc) xqA[cc] = *(const u16x4*)(pp + cc * 1024);
  }
  __syncthreads();                          // staging barrier (full, once)

  const int aoff = (lc & 3) * 272 + (lq << 4);  // A-frag: row lc -> seq lc&3 (bcast)
  const i32x4 zero4 = {0, 0, 0, 0};

#define STEP(HR, HWR, XC, XN, LT)                                              \
  {                                                                            \
    const int lt_ = (LT);                                                      \
    if (lt_ + 1 < tc) {                  /* early prefetch: next xp -> XN */   \
      const unsigned short* pp = xp + (size_t)(lt_ + 1) * 262144 + xoff;       \
      _Pragma("unroll")                                                        \
      for (int cc = 0; cc < 2; ++cc) XN[cc] = *(const u16x4*)(pp + cc * 1024); \
    }                                                                          \
    float fa = flgl[lt_ * 4 + (lc & 3)];   /* reset flag, A-row's seq */       \
    i32x4 racc[8];                                                             \
    const signed char* hbase = &(HR)[0][0];                                    \
    {                                                                          \
      i32x4 a = *(const i32x4*)(hbase + aoff);                                 \
      i32x4 am = (fa != 0.f) ? zero4 : a;                                      \
      _Pragma("unroll")                                                        \
      for (int tau = 0; tau < 8; ++tau)                                        \
        racc[tau] = __builtin_amdgcn_mfma_i32_16x16x64_i8(am, wq[tau][0], zero4, 0, 0, 0); \
    }                                                                          \
    _Pragma("unroll")                                                          \
    for (int kk = 1; kk < 4; ++kk) {                                           \
      i32x4 a = *(const i32x4*)(hbase + aoff + kk * 64);                       \
      i32x4 am = (fa != 0.f) ? zero4 : a;                                      \
      _Pragma("unroll")                                                        \
      for (int tau = 0; tau < 8; ++tau)                                        \
        racc[tau] = __builtin_amdgcn_mfma_i32_16x16x64_i8(am, wq[tau][kk], racc[tau], 0, 0, 0); \
    }                                                                          \
    i32x4 sg0 = hf ? racc[1] : racc[0];    /* static-index selects only */     \
    i32x4 sg1 = hf ? racc[3] : racc[2];                                        \
    i32x4 sg2 = hf ? racc[5] : racc[4];                                        \
    i32x4 sg3 = hf ? racc[7] : racc[6];                                        \
    signed char* hw = &(HWR)[0][0];                                            \
    signed char* hb = hbuf + ((size_t)lt_ * 256 + (s0 + sb2)) * 256 + j;       \
    _Pragma("unroll")                                                          \
    for (int cc = 0; cc < 2; ++cc) {                                           \
      int g0 = odd ? sg0[2 + cc] : sg0[cc];                                    \
      int g1 = odd ? sg1[2 + cc] : sg1[cc];                                    \
      int g2 = odd ? sg2[2 + cc] : sg2[cc];                                    \
      int g3 = odd ? sg3[2 + cc] : sg3[cc];                                    \
      u16x4 xv = XC[cc];                                                       \
      float xi = fmaf((float)g0, dsc[0], bf2f(xv.x));                          \
      float xf = fmaf((float)g1, dsc[1], bf2f(xv.y));                          \
      float xg = fmaf((float)g2, dsc[2], bf2f(xv.z));                          \
      float xo = fmaf((float)g3, dsc[3], bf2f(xv.w));                          \
      float si = frcp(1.f + fexp2(xi));                                        \
      float sf = frcp(1.f + fexp2(xf));                                        \
      float so = frcp(1.f + fexp2(xo));                                        \
      float tg = fmaf(-2.f, frcp(1.f + fexp2(xg)), 1.f);                       \
      float fr = flgl[lt_ * 4 + sb2 + cc];                                     \
      float cp = (fr != 0.f) ? 0.f : cst[cc];                                  \
      float cn = fmaf(sf, cp, si * tg);                                        \
      cst[cc] = cn;                                                            \
      float th = fmaf(-2.f, frcp(1.f + fexp2(L2E2 * cn)), 1.f);                \
      float hn = so * th;                                                      \
      signed char q8 = (signed char)(int)rintf(hn * 127.f);                    \
      hw[(sb2 + cc) * 272 + j] = q8;                                           \
      hb[cc * 256] = q8;                                                       \
      if (lt_ == tc - 1) {                                                     \
        int sg = s0 + sb2 + cc;                                                \
        hstate[(size_t)sg * 256 + j] = hn;                                     \
        cstate[(size_t)sg * 256 + j] = cn;                                     \
        if (last) {                                                            \
          out[4325376 + (size_t)sg * 256 + j] = hn;                            \
          out[4390912 + (size_t)sg * 256 + j] = cn;                            \
        }                                                                      \
      }                                                                        \
    }                                                                          \
    asm volatile("s_waitcnt lgkmcnt(0)\n\ts_barrier" ::: "memory");            \
  }

  for (int lt = 0; lt < tc; lt += 2) {     // tc even
    STEP(Hl[0], Hl[1], xqA, xqB, lt);
    STEP(Hl[1], Hl[0], xqB, xqA, lt + 1);
  }
#undef STEP
}

// --- K3 body (512 threads): heads GEMM from int8 hbuf [lt][s][j].
__device__ __forceinline__ void k3_body(int gk,
                                        const signed char* __restrict__ hbuf,
                                        const signed char* __restrict__ Wlq,
                                        const float* __restrict__ lsc,
                                        const float* __restrict__ blog,
                                        const float* __restrict__ bval,
                                        float* __restrict__ out,
                                        int t0, int tc, int tcsh) {
  const int w = threadIdx.x >> 6, l = threadIdx.x & 63;
  const int lc = l & 15, lq = l >> 4;
  const int tk = gk * 8 + w;                    // 0 .. 16*tc-1
  const int pg = tk >> tcsh, lt = tk & (tc - 1);
  const int t = t0 + lt;
  const i32x4 zero4 = {0, 0, 0, 0};

  i32x4 dacc[3] = {zero4, zero4, zero4};
  #pragma unroll
  for (int kk = 0; kk < 4; ++kk) {
    i32x4 a = *(const i32x4*)(hbuf + ((size_t)lt * 256 + (pg << 4) + lc) * 256
                              + kk * 64 + (lq << 4));
    #pragma unroll
    for (int n = 0; n < 3; ++n) {
      int row = n * 16 + lc;
      i32x4 bf = (row < 33) ? *(const i32x4*)(Wlq + (size_t)row * 256 + kk * 64 + (lq << 4))
                            : zero4;
      dacc[n] = __builtin_amdgcn_mfma_i32_16x16x64_i8(a, bf, dacc[n], 0, 0, 0);
    }
  }
  #pragma unroll
  for (int n = 0; n < 2; ++n) {
    float dsn = lsc[n * 16 + lc] * (1.f / 127.f);
    float lbn = blog[n * 16 + lc];
    #pragma unroll
    for (int r = 0; r < 4; ++r) {
      int sg = (pg << 4) + lq * 4 + r;
      out[((size_t)sg * 512 + t) * 32 + n * 16 + lc] = fmaf((float)dacc[n][r], dsn, lbn);
    }
  }
  if (lc == 0) {
    float ds2 = lsc[32] * (1.f / 127.f);
    float b2 = bval[0];
    #pragma unroll
    for (int r = 0; r < 4; ++r) {
      int sg = (pg << 4) + lq * 4 + r;
      out[4194304 + (size_t)sg * 512 + t] = fmaf((float)dacc[2][r], ds2, b2);
    }
  }
}

// ================================================================ MEGA
// smem = 80 KB: forces 1 block/CU so k2 blocks own their CUs exclusively
// (k1-wave MFMA/LDS contention on k2 CUs was the R8 residual suspect).
__launch_bounds__(512, 2)
__global__ void mega(int nk2, int t0_2, const unsigned short* xp2, signed char* hb2,
                     int nk1, int t0_1, unsigned short* xp1,
                     int nk3, int t0_3, const signed char* hb3,
                     const float* feat, const float* Wih,
                     const float* bih, const float* bhh,
                     const signed char* Wq, const float* wsc,
                     const signed char* Wlq, const float* lsc,
                     const float* ep, const float* h0, const float* c0,
                     const float* blog, const float* bval,
                     float* hstate, float* cstate, float* out,
                     int tc, int tcsh) {
  __shared__ __align__(16) char smem[81920];
  int bid = (int)blockIdx.x;
  if (bid < nk2) {
    k2_body(bid, smem, xp2, Wq, wsc, ep, h0, c0, hstate, cstate, hb2, out, t0_2, tc);
  } else if (bid < nk2 + nk1) {
    k1_body(bid - nk2, smem, feat, Wih, bih, bhh, xp1, t0_1);
  } else {
    k3_body(bid - nk2 - nk1, hb3, Wlq, lsc, blog, bval, out, t0_3, tc, tcsh);
  }
}

// ---------------------------------------------------------------- launcher
extern "C" void kernel_launch(void* const* d_in, const int* in_sizes, int n_in,
                              void* d_out, int out_size, void* d_ws, size_t ws_size,
                              hipStream_t stream) {
  const float* feat = (const float*)d_in[0];
  const float* ep   = (const float*)d_in[1];
  const float* h0   = (const float*)d_in[2];
  const float* c0   = (const float*)d_in[3];
  const float* Wih  = (const float*)d_in[4];
  const float* Whh  = (const float*)d_in[5];
  const float* bih  = (const float*)d_in[6];
  const float* bhh  = (const float*)d_in[7];
  const float* Wlog = (const float*)d_in[8];
  const float* blog = (const float*)d_in[9];
  const float* Wval = (const float*)d_in[10];
  const float* bval = (const float*)d_in[11];
  float* out = (float*)d_out;
  char* ws = (char*)d_ws;
  signed char* Wq     = (signed char*)(ws + 0);        // 262144
  float*       wsc    = (float*)      (ws + 262144);   // 4096
  signed char* Wlq    = (signed char*)(ws + 266240);   // 8448
  float*       lsc    = (float*)      (ws + 274688);   // 132
  float*       hstate = (float*)      (ws + 275456);   // 262144
  float*       cstate = (float*)      (ws + 537600);   // 262144 (ends 799744)

  // Tc chosen so 1MiB + 2*Tc*(512KiB xp + 64KiB hbuf) <= ws_size; Tc<=128.
  int Tc = 128;
  while (Tc > 16 && (size_t)1048576 + (size_t)Tc * 1179648 > ws_size) Tc >>= 1;
  int tcsh = 31 - __builtin_clz(Tc);
  int nc = 512 / Tc;
  size_t xpsz = (size_t)Tc * 524288, hbsz = (size_t)Tc * 65536;
  unsigned short* xpb[2] = { (unsigned short*)(ws + 1048576),
                             (unsigned short*)(ws + 1048576 + xpsz) };
  signed char*    hbb[2] = { (signed char*)(ws + 1048576 + 2 * xpsz),
                             (signed char*)(ws + 1048576 + 2 * xpsz + hbsz) };
  const int NK1 = Tc * 16;   // k1 tiles: (Tc*256/128 m-tiles) * 8 bn
  const int NK3 = Tc * 2;    // k3: 16*Tc wave-tasks / 8 waves
  const int NK2 = 64;

  hipLaunchKernelGGL(k0_quant, dim3(1057), dim3(64), 0, stream,
                     Whh, Wlog, Wval, Wq, wsc, Wlq, lsc);
  // lead-in: k1 for chunk 0
  hipLaunchKernelGGL(mega, dim3(NK1), dim3(512), 0, stream,
                     0, 0, xpb[0], hbb[0],
                     NK1, 0, xpb[0],
                     0, 0, hbb[0],
                     feat, Wih, bih, bhh, Wq, wsc, Wlq, lsc, ep, h0, c0,
                     blog, bval, hstate, cstate, out, Tc, tcsh);
  for (int j = 0; j < nc; ++j) {
    int nk1 = (j + 1 < nc) ? NK1 : 0;
    int nk3 = (j >= 1) ? NK3 : 0;
    hipLaunchKernelGGL(mega, dim3(NK2 + nk1 + nk3), dim3(512), 0, stream,
                       NK2, j * Tc, xpb[j & 1], hbb[j & 1],
                       nk1, (j + 1) * Tc, xpb[(j + 1) & 1],
                       nk3, (j - 1) * Tc, hbb[(j + 1) & 1],   // (j-1)&1 == (j+1)&1
                       feat, Wih, bih, bhh, Wq, wsc, Wlq, lsc, ep, h0, c0,
                       blog, bval, hstate, cstate, out, Tc, tcsh);
  }
  // tail: k3 for last chunk
  hipLaunchKernelGGL(mega, dim3(NK3), dim3(512), 0, stream,
                     0, 0, xpb[0], hbb[0],
                     0, 0, xpb[0],
                     NK3, (nc - 1) * Tc, hbb[(nc - 1) & 1],
                     feat, Wih, bih, bhh, Wq, wsc, Wlq, lsc, ep, h0, c0,
                     blog, bval, hstate, cstate, out, Tc, tcsh);
}

// Round 10
// 551.045 us; speedup vs baseline: 1.1127x; 1.1127x over previous
//
#include <hip/hip_runtime.h>
#include <hip/hip_bf16.h>

// ACLSTM on MI355X — persistent-RNN, time-chunked + software-pipelined.
// R10: k2 = 64 blocks x 4 seqs, 1024 threads (16 waves, 4/SIMD), 1 cell/lane.
//      - wave w owns 16 cols x 4 gammas: 16 MFMAs/wave (64/SIMD unchanged);
//        4 waves/SIMD double latency-hiding of the serial chain (R9 proved
//        the step is latency- not throughput-bound: CU-exclusive was a no-op).
//      - per lane 1 cell (seq=reg mapping -> 3-cndmask static select).
//      - wq = 64 VGPR -> weights stay register-resident (R8/9 VGPR=108 < 128
//        showed the compiler was re-fetching fragments every step).
//      k1/k3 bodies unchanged, guarded for 1024-thread blocks.

typedef float f32x4 __attribute__((ext_vector_type(4)));
typedef int   i32x4 __attribute__((ext_vector_type(4)));
typedef short s16x8 __attribute__((ext_vector_type(8)));
typedef short s16x4 __attribute__((ext_vector_type(4)));
typedef unsigned short u16x4 __attribute__((ext_vector_type(4)));

#define L2E   1.44269504088896340736f
#define L2E2  2.88539008177792681472f

__device__ __forceinline__ float fexp2(float x) {
#if __has_builtin(__builtin_amdgcn_exp2f)
  return __builtin_amdgcn_exp2f(x);
#else
  float r; asm("v_exp_f32 %0, %1" : "=v"(r) : "v"(x)); return r;
#endif
}
__device__ __forceinline__ float frcp(float x) { return __builtin_amdgcn_rcpf(x); }
__device__ __forceinline__ float bf2f(unsigned short u) {
  return __uint_as_float(((unsigned)u) << 16);
}
__device__ __forceinline__ unsigned short f2bf(float f) {   // RNE f32->bf16
  unsigned int b = __float_as_uint(f);
  return (unsigned short)((b + 0x7FFFu + ((b >> 16) & 1u)) >> 16);
}

// ---------------------------------------------------------------- K0: quant
__global__ void k0_quant(const float* __restrict__ Whh,
                         const float* __restrict__ Wlog,
                         const float* __restrict__ Wval,
                         signed char* __restrict__ Wq, float* __restrict__ wsc,
                         signed char* __restrict__ Wlq, float* __restrict__ lsc) {
  int r = blockIdx.x, l = threadIdx.x;   // 1057 rows, 64 lanes
  const float* src; signed char* dst; float* sd;
  if (r < 1024) { src = Whh + (size_t)r * 256; dst = Wq + (size_t)r * 256; sd = wsc + r; }
  else {
    int hr = r - 1024;
    src = (hr < 32) ? (Wlog + (size_t)hr * 256) : Wval;
    dst = Wlq + (size_t)hr * 256; sd = lsc + hr;
  }
  f32x4 v = *(const f32x4*)(src + l * 4);
  float m = fmaxf(fmaxf(fabsf(v.x), fabsf(v.y)), fmaxf(fabsf(v.z), fabsf(v.w)));
  #pragma unroll
  for (int off = 32; off; off >>= 1) m = fmaxf(m, __shfl_xor(m, off));
  float inv = (m > 0.f) ? (127.f / m) : 0.f;
  int q0 = (int)rintf(v.x * inv), q1 = (int)rintf(v.y * inv);
  int q2 = (int)rintf(v.z * inv), q3 = (int)rintf(v.w * inv);
  unsigned int pk = (q0 & 255) | ((q1 & 255) << 8) | ((q2 & 255) << 16) | ((q3 & 255) << 24);
  *(unsigned int*)(dst + l * 4) = pk;
  if (l == 0) *sd = m * (1.f / 127.f);
}

// ================================================================ bodies
// --- K1 body (512 active of 1024 threads): M=128 x N=128(=32j x 4gm).
__device__ __forceinline__ void k1_body(int gk, char* smem,
                                        const float* __restrict__ feat,
                                        const float* __restrict__ Wih,
                                        const float* __restrict__ bih,
                                        const float* __restrict__ bhh,
                                        unsigned short* __restrict__ xp, int t0) {
  short (*Bl)[136] = (short (*)[136])smem;                  // 128x136 = 34816 B
  float* bias = (float*)(smem + 34816);                     // 512 B
  const int tid = threadIdx.x;
  const int bm = gk >> 3, bn = gk & 7;
  const int m0 = bm << 7, j0 = bn << 5;
  const int tg = t0 + (bm >> 1), sbase = (bm & 1) << 7;     // 128 | 256
  s16x8 a[4];
  if (tid < 512) {
    #pragma unroll
    for (int it = 0; it < 8; ++it) {             // B: 128 g-rows x 128 k
      int idx = it * 512 + tid;
      int rr = idx >> 5, c4 = (idx & 31) << 2;
      int g = ((rr & 3) << 8) + j0 + (rr >> 2);
      f32x4 v = *(const f32x4*)(Wih + (size_t)g * 128 + c4);
      s16x4 pk = { (short)f2bf(v.x), (short)f2bf(v.y), (short)f2bf(v.z), (short)f2bf(v.w) };
      *(s16x4*)&Bl[rr][c4] = pk;
    }
    if (tid < 128) {
      int g = ((tid & 3) << 8) + j0 + (tid >> 2);
      bias[tid] = bih[g] + bhh[g];
    }
    const int w = tid >> 6, l = tid & 63;
    const int lr = l & 15, lk8 = (l >> 4) << 3;
    const float* fp = feat + ((size_t)(sbase + (w << 4) + lr) * 512 + tg) * 128 + lk8;
    #pragma unroll
    for (int kk = 0; kk < 4; ++kk) {
      f32x4 v0 = *(const f32x4*)(fp + kk * 32);
      f32x4 v1 = *(const f32x4*)(fp + kk * 32 + 4);
      s16x8 pk = { (short)f2bf(v0.x), (short)f2bf(v0.y), (short)f2bf(v0.z), (short)f2bf(v0.w),
                   (short)f2bf(v1.x), (short)f2bf(v1.y), (short)f2bf(v1.z), (short)f2bf(v1.w) };
      a[kk] = pk;
    }
  }
  __syncthreads();
  if (tid >= 512) return;
  const int w = tid >> 6, l = tid & 63;
  const int lr = l & 15, lk8 = (l >> 4) << 3;
  f32x4 z = {0.f, 0.f, 0.f, 0.f};
  f32x4 acc[8];
  #pragma unroll
  for (int nt = 0; nt < 8; ++nt) acc[nt] = z;
  #pragma unroll
  for (int kk = 0; kk < 4; ++kk) {
    #pragma unroll
    for (int nt = 0; nt < 8; ++nt) {
      s16x8 bb = *(const s16x8*)&Bl[nt * 16 + lr][kk * 32 + lk8];
      acc[nt] = __builtin_amdgcn_mfma_f32_16x16x32_bf16(a[kk], bb, acc[nt], 0, 0, 0);
    }
  }
  #pragma unroll
  for (int nt = 0; nt < 8; ++nt) {
    #pragma unroll
    for (int r = 0; r < 4; ++r) {
      int m = m0 + (w << 4) + (l >> 4) * 4 + r;   // chunk-local
      int c = nt * 16 + lr;
      float gsc = ((c & 3) == 2) ? L2E2 : -L2E;
      float val = (acc[nt][r] + bias[c]) * gsc;
      xp[(size_t)m * 1024 + (j0 << 2) + c] = f2bf(val);
    }
  }
}

// --- K2 body: 64 blocks x 4 seqs, 1024 threads, 1 cell/lane.
__device__ __forceinline__ void k2_body(int bid, char* smem,
                                        const unsigned short* __restrict__ xp,
                                        const signed char* __restrict__ Wq,
                                        const float* __restrict__ wsc,
                                        const float* __restrict__ ep,
                                        const float* __restrict__ h0,
                                        const float* __restrict__ c0,
                                        float* __restrict__ hstate,
                                        float* __restrict__ cstate,
                                        signed char* __restrict__ hbuf,
                                        float* __restrict__ out, int t0, int tc) {
  __builtin_amdgcn_s_setprio(3);
  signed char (*Hl)[4][272] = (signed char (*)[4][272])smem;  // 2x4x272 = 2176
  float* flgl = (float*)(smem + 2176);     // [lt][4] flags, tc*16 B
  const int tid = threadIdx.x;             // 0..1023
  const int w = tid >> 6, l = tid & 63;    // w: 0..15
  const int lc = l & 15, lq = l >> 4;
  const int j = (w << 4) + lc;             // lane's h-column, 0..255
  const int s0 = bid << 2;
  const bool last = (t0 + tc == 512);

  {                                        // stage h rows 0..3 (int8)
    const float* hsrc = (t0 == 0) ? h0 : hstate;
    int s = tid >> 8, jj = tid & 255;
    float v = hsrc[(size_t)(s0 + s) * 256 + jj];
    float q = rintf(fminf(fmaxf(v * 127.f, -127.f), 127.f));
    Hl[0][s][jj] = (signed char)(int)q;
  }
  {                                        // stage episode flags [lt][4]
    int n = tc << 2;
    for (int idx = tid; idx < n; idx += 1024) {
      int s = idx & 3, llt = idx >> 2;
      flgl[idx] = ep[(size_t)(s0 + s) * 512 + t0 + llt];
    }
  }

  i32x4 wq[4][4];                          // persistent W_hh fragments (64 VGPR)
  #pragma unroll
  for (int g = 0; g < 4; ++g)
    #pragma unroll
    for (int kk = 0; kk < 4; ++kk)
      wq[g][kk] = *(const i32x4*)(Wq + (size_t)(g * 256 + j) * 256 + kk * 64 + (lq << 4));
  float dsc[4];
  #pragma unroll
  for (int g = 0; g < 4; ++g) {
    float sgn = (g == 2) ? L2E2 : -L2E;
    dsc[g] = sgn * wsc[g * 256 + j] * (1.f / 127.f);
  }

  float cst;                               // c state: seq s0+lq, col j
  {
    const float* csrc = (t0 == 0) ? c0 : cstate;
    cst = csrc[(size_t)(s0 + lq) * 256 + j];
  }

  const size_t xoff = ((size_t)(s0 + lq) * 256 + j) * 4;
  u16x4 xqA, xqB;
  xqA = *(const u16x4*)(xp + xoff);        // lt = 0
  __syncthreads();                          // staging barrier (full, once)

  const int aoff = (lc & 3) * 272 + (lq << 4);  // A-frag: row lc -> seq lc&3 (bcast)
  const i32x4 zero4 = {0, 0, 0, 0};

#define STEP(HR, HWR, XC, XN, LT)                                              \
  {                                                                            \
    const int lt_ = (LT);                                                      \
    if (lt_ + 1 < tc)                    /* early prefetch: next xp -> XN */   \
      XN = *(const u16x4*)(xp + (size_t)(lt_ + 1) * 262144 + xoff);            \
    float fa = flgl[lt_ * 4 + (lc & 3)];   /* reset flag, A-row's seq */       \
    i32x4 racc[4];                                                             \
    const signed char* hbase = &(HR)[0][0];                                    \
    {                                                                          \
      i32x4 a = *(const i32x4*)(hbase + aoff);                                 \
      i32x4 am = (fa != 0.f) ? zero4 : a;                                      \
      _Pragma("unroll")                                                        \
      for (int g = 0; g < 4; ++g)                                              \
        racc[g] = __builtin_amdgcn_mfma_i32_16x16x64_i8(am, wq[g][0], zero4, 0, 0, 0); \
    }                                                                          \
    _Pragma("unroll")                                                          \
    for (int kk = 1; kk < 4; ++kk) {                                           \
      i32x4 a = *(const i32x4*)(hbase + aoff + kk * 64);                       \
      i32x4 am = (fa != 0.f) ? zero4 : a;                                      \
      _Pragma("unroll")                                                        \
      for (int g = 0; g < 4; ++g)                                              \
        racc[g] = __builtin_amdgcn_mfma_i32_16x16x64_i8(am, wq[g][kk], racc[g], 0, 0, 0); \
    }                                                                          \
    /* select seq lq from C rows (seq == reg): 3 static cndmasks per gamma */  \
    int r01_0 = (lq & 1) ? racc[0][1] : racc[0][0];                            \
    int r23_0 = (lq & 1) ? racc[0][3] : racc[0][2];                            \
    int g0 = (lq & 2) ? r23_0 : r01_0;                                         \
    int r01_1 = (lq & 1) ? racc[1][1] : racc[1][0];                            \
    int r23_1 = (lq & 1) ? racc[1][3] : racc[1][2];                            \
    int g1 = (lq & 2) ? r23_1 : r01_1;                                         \
    int r01_2 = (lq & 1) ? racc[2][1] : racc[2][0];                            \
    int r23_2 = (lq & 1) ? racc[2][3] : racc[2][2];                            \
    int g2 = (lq & 2) ? r23_2 : r01_2;                                         \
    int r01_3 = (lq & 1) ? racc[3][1] : racc[3][0];                            \
    int r23_3 = (lq & 1) ? racc[3][3] : racc[3][2];                            \
    int g3 = (lq & 2) ? r23_3 : r01_3;                                         \
    u16x4 xv = XC;                                                             \
    float xi = fmaf((float)g0, dsc[0], bf2f(xv.x));                            \
    float xf = fmaf((float)g1, dsc[1], bf2f(xv.y));                            \
    float xg = fmaf((float)g2, dsc[2], bf2f(xv.z));                            \
    float xo = fmaf((float)g3, dsc[3], bf2f(xv.w));                            \
    float si = frcp(1.f + fexp2(xi));                                          \
    float sf = frcp(1.f + fexp2(xf));                                          \
    float so = frcp(1.f + fexp2(xo));                                          \
    float tg = fmaf(-2.f, frcp(1.f + fexp2(xg)), 1.f);                         \
    float fr = flgl[lt_ * 4 + lq];                                             \
    float cp = (fr != 0.f) ? 0.f : cst;                                        \
    float cn = fmaf(sf, cp, si * tg);                                          \
    cst = cn;                                                                  \
    float th = fmaf(-2.f, frcp(1.f + fexp2(L2E2 * cn)), 1.f);                  \
    float hn = so * th;                                                        \
    signed char q8 = (signed char)(int)rintf(hn * 127.f);                      \
    (&(HWR)[0][0])[lq * 272 + j] = q8;                                         \
    hbuf[((size_t)lt_ * 256 + s0 + lq) * 256 + j] = q8;                        \
    if (lt_ == tc - 1) {                                                       \
      int sq = s0 + lq;                                                        \
      hstate[(size_t)sq * 256 + j] = hn;                                       \
      cstate[(size_t)sq * 256 + j] = cn;                                       \
      if (last) {                                                              \
        out[4325376 + (size_t)sq * 256 + j] = hn;                              \
        out[4390912 + (size_t)sq * 256 + j] = cn;                              \
      }                                                                        \
    }                                                                          \
    asm volatile("s_waitcnt lgkmcnt(0)\n\ts_barrier" ::: "memory");            \
  }

  for (int lt = 0; lt < tc; lt += 2) {     // tc even
    STEP(Hl[0], Hl[1], xqA, xqB, lt);
    STEP(Hl[1], Hl[0], xqB, xqA, lt + 1);
  }
#undef STEP
}

// --- K3 body (512 active of 1024): heads GEMM from int8 hbuf [lt][s][j].
__device__ __forceinline__ void k3_body(int gk,
                                        const signed char* __restrict__ hbuf,
                                        const signed char* __restrict__ Wlq,
                                        const float* __restrict__ lsc,
                                        const float* __restrict__ blog,
                                        const float* __restrict__ bval,
                                        float* __restrict__ out,
                                        int t0, int tc, int tcsh) {
  if (threadIdx.x >= 512) return;
  const int w = threadIdx.x >> 6, l = threadIdx.x & 63;
  const int lc = l & 15, lq = l >> 4;
  const int tk = gk * 8 + w;                    // 0 .. 16*tc-1
  const int pg = tk >> tcsh, lt = tk & (tc - 1);
  const int t = t0 + lt;
  const i32x4 zero4 = {0, 0, 0, 0};

  i32x4 dacc[3] = {zero4, zero4, zero4};
  #pragma unroll
  for (int kk = 0; kk < 4; ++kk) {
    i32x4 a = *(const i32x4*)(hbuf + ((size_t)lt * 256 + (pg << 4) + lc) * 256
                              + kk * 64 + (lq << 4));
    #pragma unroll
    for (int n = 0; n < 3; ++n) {
      int row = n * 16 + lc;
      i32x4 bf = (row < 33) ? *(const i32x4*)(Wlq + (size_t)row * 256 + kk * 64 + (lq << 4))
                            : zero4;
      dacc[n] = __builtin_amdgcn_mfma_i32_16x16x64_i8(a, bf, dacc[n], 0, 0, 0);
    }
  }
  #pragma unroll
  for (int n = 0; n < 2; ++n) {
    float dsn = lsc[n * 16 + lc] * (1.f / 127.f);
    float lbn = blog[n * 16 + lc];
    #pragma unroll
    for (int r = 0; r < 4; ++r) {
      int sg = (pg << 4) + lq * 4 + r;
      out[((size_t)sg * 512 + t) * 32 + n * 16 + lc] = fmaf((float)dacc[n][r], dsn, lbn);
    }
  }
  if (lc == 0) {
    float ds2 = lsc[32] * (1.f / 127.f);
    float b2 = bval[0];
    #pragma unroll
    for (int r = 0; r < 4; ++r) {
      int sg = (pg << 4) + lq * 4 + r;
      out[4194304 + (size_t)sg * 512 + t] = fmaf((float)dacc[2][r], ds2, b2);
    }
  }
}

// ================================================================ MEGA
__launch_bounds__(1024, 1)
__global__ void mega(int nk2, int t0_2, const unsigned short* xp2, signed char* hb2,
                     int nk1, int t0_1, unsigned short* xp1,
                     int nk3, int t0_3, const signed char* hb3,
                     const float* feat, const float* Wih,
                     const float* bih, const float* bhh,
                     const signed char* Wq, const float* wsc,
                     const signed char* Wlq, const float* lsc,
                     const float* ep, const float* h0, const float* c0,
                     const float* blog, const float* bval,
                     float* hstate, float* cstate, float* out,
                     int tc, int tcsh) {
  __shared__ __align__(16) char smem[35840];
  int bid = (int)blockIdx.x;
  if (bid < nk2) {
    k2_body(bid, smem, xp2, Wq, wsc, ep, h0, c0, hstate, cstate, hb2, out, t0_2, tc);
  } else if (bid < nk2 + nk1) {
    k1_body(bid - nk2, smem, feat, Wih, bih, bhh, xp1, t0_1);
  } else {
    k3_body(bid - nk2 - nk1, hb3, Wlq, lsc, blog, bval, out, t0_3, tc, tcsh);
  }
}

// ---------------------------------------------------------------- launcher
extern "C" void kernel_launch(void* const* d_in, const int* in_sizes, int n_in,
                              void* d_out, int out_size, void* d_ws, size_t ws_size,
                              hipStream_t stream) {
  const float* feat = (const float*)d_in[0];
  const float* ep   = (const float*)d_in[1];
  const float* h0   = (const float*)d_in[2];
  const float* c0   = (const float*)d_in[3];
  const float* Wih  = (const float*)d_in[4];
  const float* Whh  = (const float*)d_in[5];
  const float* bih  = (const float*)d_in[6];
  const float* bhh  = (const float*)d_in[7];
  const float* Wlog = (const float*)d_in[8];
  const float* blog = (const float*)d_in[9];
  const float* Wval = (const float*)d_in[10];
  const float* bval = (const float*)d_in[11];
  float* out = (float*)d_out;
  char* ws = (char*)d_ws;
  signed char* Wq     = (signed char*)(ws + 0);        // 262144
  float*       wsc    = (float*)      (ws + 262144);   // 4096
  signed char* Wlq    = (signed char*)(ws + 266240);   // 8448
  float*       lsc    = (float*)      (ws + 274688);   // 132
  float*       hstate = (float*)      (ws + 275456);   // 262144
  float*       cstate = (float*)      (ws + 537600);   // 262144 (ends 799744)

  // Tc chosen so 1MiB + 2*Tc*(512KiB xp + 64KiB hbuf) <= ws_size; Tc<=128.
  int Tc = 128;
  while (Tc > 16 && (size_t)1048576 + (size_t)Tc * 1179648 > ws_size) Tc >>= 1;
  int tcsh = 31 - __builtin_clz(Tc);
  int nc = 512 / Tc;
  size_t xpsz = (size_t)Tc * 524288, hbsz = (size_t)Tc * 65536;
  unsigned short* xpb[2] = { (unsigned short*)(ws + 1048576),
                             (unsigned short*)(ws + 1048576 + xpsz) };
  signed char*    hbb[2] = { (signed char*)(ws + 1048576 + 2 * xpsz),
                             (signed char*)(ws + 1048576 + 2 * xpsz + hbsz) };
  const int NK1 = Tc * 16;   // k1 tiles: (Tc*256/128 m-tiles) * 8 bn
  const int NK3 = Tc * 2;    // k3: 16*Tc wave-tasks / 8 waves
  const int NK2 = 64;

  hipLaunchKernelGGL(k0_quant, dim3(1057), dim3(64), 0, stream,
                     Whh, Wlog, Wval, Wq, wsc, Wlq, lsc);
  // lead-in: k1 for chunk 0
  hipLaunchKernelGGL(mega, dim3(NK1), dim3(1024), 0, stream,
                     0, 0, xpb[0], hbb[0],
                     NK1, 0, xpb[0],
                     0, 0, hbb[0],
                     feat, Wih, bih, bhh, Wq, wsc, Wlq, lsc, ep, h0, c0,
                     blog, bval, hstate, cstate, out, Tc, tcsh);
  for (int j = 0; j < nc; ++j) {
    int nk1 = (j + 1 < nc) ? NK1 : 0;
    int nk3 = (j >= 1) ? NK3 : 0;
    hipLaunchKernelGGL(mega, dim3(NK2 + nk1 + nk3), dim3(1024), 0, stream,
                       NK2, j * Tc, xpb[j & 1], hbb[j & 1],
                       nk1, (j + 1) * Tc, xpb[(j + 1) & 1],
                       nk3, (j - 1) * Tc, hbb[(j + 1) & 1],   // (j-1)&1 == (j+1)&1
                       feat, Wih, bih, bhh, Wq, wsc, Wlq, lsc, ep, h0, c0,
                       blog, bval, hstate, cstate, out, Tc, tcsh);
  }
  // tail: k3 for last chunk
  hipLaunchKernelGGL(mega, dim3(NK3), dim3(1024), 0, stream,
                     0, 0, xpb[0], hbb[0],
                     0, 0, xpb[0],
                     NK3, (nc - 1) * Tc, hbb[(nc - 1) & 1],
                     feat, Wih, bih, bhh, Wq, wsc, Wlq, lsc, ep, h0, c0,
                     blog, bval, hstate, cstate, out, Tc, tcsh);
}

// Round 13
// 548.880 us; speedup vs baseline: 1.1171x; 1.0039x over previous
//
#include <hip/hip_runtime.h>
#include <hip/hip_bf16.h>

// ACLSTM on MI355X — persistent-RNN, time-chunked + software-pipelined.
// R13: revert to R10-PASS structure (sdot4 rounds R11/R12 failed to LOAD —
//      absmax matched the empty-stub value exactly -> unsupported instr on
//      gfx950; never build on primitives absent from the ISA reference).
//      Two canary-checked trims on the proven k2:
//      (1) episode-flag prefetch into registers (the per-step LDS flag read
//          sat on the critical chain feeding MFMA #1's mask);
//      (2) magic-FMA int8 quant (RNE-identical to rintf, ~3 VALU shorter).
//      absmax must remain exactly 0.01074219.

typedef float f32x4 __attribute__((ext_vector_type(4)));
typedef int   i32x4 __attribute__((ext_vector_type(4)));
typedef short s16x8 __attribute__((ext_vector_type(8)));
typedef short s16x4 __attribute__((ext_vector_type(4)));
typedef unsigned short u16x4 __attribute__((ext_vector_type(4)));

#define L2E   1.44269504088896340736f
#define L2E2  2.88539008177792681472f
#define MAGIC 12582912.f                      // 1.5 * 2^23

__device__ __forceinline__ float fexp2(float x) {
#if __has_builtin(__builtin_amdgcn_exp2f)
  return __builtin_amdgcn_exp2f(x);
#else
  float r; asm("v_exp_f32 %0, %1" : "=v"(r) : "v"(x)); return r;
#endif
}
__device__ __forceinline__ float frcp(float x) { return __builtin_amdgcn_rcpf(x); }
__device__ __forceinline__ float bf2f(unsigned short u) {
  return __uint_as_float(((unsigned)u) << 16);
}
__device__ __forceinline__ unsigned short f2bf(float f) {   // RNE f32->bf16
  unsigned int b = __float_as_uint(f);
  return (unsigned short)((b + 0x7FFFu + ((b >> 16) & 1u)) >> 16);
}

// ---------------------------------------------------------------- K0: quant
__global__ void k0_quant(const float* __restrict__ Whh,
                         const float* __restrict__ Wlog,
                         const float* __restrict__ Wval,
                         signed char* __restrict__ Wq, float* __restrict__ wsc,
                         signed char* __restrict__ Wlq, float* __restrict__ lsc) {
  int r = blockIdx.x, l = threadIdx.x;   // 1057 rows, 64 lanes
  const float* src; signed char* dst; float* sd;
  if (r < 1024) { src = Whh + (size_t)r * 256; dst = Wq + (size_t)r * 256; sd = wsc + r; }
  else {
    int hr = r - 1024;
    src = (hr < 32) ? (Wlog + (size_t)hr * 256) : Wval;
    dst = Wlq + (size_t)hr * 256; sd = lsc + hr;
  }
  f32x4 v = *(const f32x4*)(src + l * 4);
  float m = fmaxf(fmaxf(fabsf(v.x), fabsf(v.y)), fmaxf(fabsf(v.z), fabsf(v.w)));
  #pragma unroll
  for (int off = 32; off; off >>= 1) m = fmaxf(m, __shfl_xor(m, off));
  float inv = (m > 0.f) ? (127.f / m) : 0.f;
  int q0 = (int)rintf(v.x * inv), q1 = (int)rintf(v.y * inv);
  int q2 = (int)rintf(v.z * inv), q3 = (int)rintf(v.w * inv);
  unsigned int pk = (q0 & 255) | ((q1 & 255) << 8) | ((q2 & 255) << 16) | ((q3 & 255) << 24);
  *(unsigned int*)(dst + l * 4) = pk;
  if (l == 0) *sd = m * (1.f / 127.f);
}

// ================================================================ bodies
// --- K1 body (512 active of 1024 threads): M=128 x N=128(=32j x 4gm).
__device__ __forceinline__ void k1_body(int gk, char* smem,
                                        const float* __restrict__ feat,
                                        const float* __restrict__ Wih,
                                        const float* __restrict__ bih,
                                        const float* __restrict__ bhh,
                                        unsigned short* __restrict__ xp, int t0) {
  short (*Bl)[136] = (short (*)[136])smem;                  // 128x136 = 34816 B
  float* bias = (float*)(smem + 34816);                     // 512 B
  const int tid = threadIdx.x;
  const int bm = gk >> 3, bn = gk & 7;
  const int m0 = bm << 7, j0 = bn << 5;
  const int tg = t0 + (bm >> 1), sbase = (bm & 1) << 7;     // 128 | 256
  s16x8 a[4];
  if (tid < 512) {
    #pragma unroll
    for (int it = 0; it < 8; ++it) {             // B: 128 g-rows x 128 k
      int idx = it * 512 + tid;
      int rr = idx >> 5, c4 = (idx & 31) << 2;
      int g = ((rr & 3) << 8) + j0 + (rr >> 2);
      f32x4 v = *(const f32x4*)(Wih + (size_t)g * 128 + c4);
      s16x4 pk = { (short)f2bf(v.x), (short)f2bf(v.y), (short)f2bf(v.z), (short)f2bf(v.w) };
      *(s16x4*)&Bl[rr][c4] = pk;
    }
    if (tid < 128) {
      int g = ((tid & 3) << 8) + j0 + (tid >> 2);
      bias[tid] = bih[g] + bhh[g];
    }
    const int w = tid >> 6, l = tid & 63;
    const int lr = l & 15, lk8 = (l >> 4) << 3;
    const float* fp = feat + ((size_t)(sbase + (w << 4) + lr) * 512 + tg) * 128 + lk8;
    #pragma unroll
    for (int kk = 0; kk < 4; ++kk) {
      f32x4 v0 = *(const f32x4*)(fp + kk * 32);
      f32x4 v1 = *(const f32x4*)(fp + kk * 32 + 4);
      s16x8 pk = { (short)f2bf(v0.x), (short)f2bf(v0.y), (short)f2bf(v0.z), (short)f2bf(v0.w),
                   (short)f2bf(v1.x), (short)f2bf(v1.y), (short)f2bf(v1.z), (short)f2bf(v1.w) };
      a[kk] = pk;
    }
  }
  __syncthreads();
  if (tid >= 512) return;
  const int w = tid >> 6, l = tid & 63;
  const int lr = l & 15, lk8 = (l >> 4) << 3;
  f32x4 z = {0.f, 0.f, 0.f, 0.f};
  f32x4 acc[8];
  #pragma unroll
  for (int nt = 0; nt < 8; ++nt) acc[nt] = z;
  #pragma unroll
  for (int kk = 0; kk < 4; ++kk) {
    #pragma unroll
    for (int nt = 0; nt < 8; ++nt) {
      s16x8 bb = *(const s16x8*)&Bl[nt * 16 + lr][kk * 32 + lk8];
      acc[nt] = __builtin_amdgcn_mfma_f32_16x16x32_bf16(a[kk], bb, acc[nt], 0, 0, 0);
    }
  }
  #pragma unroll
  for (int nt = 0; nt < 8; ++nt) {
    #pragma unroll
    for (int r = 0; r < 4; ++r) {
      int m = m0 + (w << 4) + (l >> 4) * 4 + r;   // chunk-local
      int c = nt * 16 + lr;
      float gsc = ((c & 3) == 2) ? L2E2 : -L2E;
      float val = (acc[nt][r] + bias[c]) * gsc;
      xp[(size_t)m * 1024 + (j0 << 2) + c] = f2bf(val);
    }
  }
}

// --- K2 body: 64 blocks x 4 seqs, 1024 threads, 1 cell/lane (R10 core).
__device__ __forceinline__ void k2_body(int bid, char* smem,
                                        const unsigned short* __restrict__ xp,
                                        const signed char* __restrict__ Wq,
                                        const float* __restrict__ wsc,
                                        const float* __restrict__ ep,
                                        const float* __restrict__ h0,
                                        const float* __restrict__ c0,
                                        float* __restrict__ hstate,
                                        float* __restrict__ cstate,
                                        signed char* __restrict__ hbuf,
                                        float* __restrict__ out, int t0, int tc) {
  __builtin_amdgcn_s_setprio(3);
  signed char (*Hl)[4][272] = (signed char (*)[4][272])smem;  // 2x4x272 = 2176
  float* flgl = (float*)(smem + 2176);     // [lt][4] flags, tc*16 B
  const int tid = threadIdx.x;             // 0..1023
  const int w = tid >> 6, l = tid & 63;    // w: 0..15
  const int lc = l & 15, lq = l >> 4;
  const int j = (w << 4) + lc;             // lane's h-column, 0..255
  const int s0 = bid << 2;
  const bool last = (t0 + tc == 512);

  {                                        // stage h rows 0..3 (int8)
    const float* hsrc = (t0 == 0) ? h0 : hstate;
    int s = tid >> 8, jj = tid & 255;
    float v = hsrc[(size_t)(s0 + s) * 256 + jj];
    float q = rintf(fminf(fmaxf(v * 127.f, -127.f), 127.f));
    Hl[0][s][jj] = (signed char)(int)q;
  }
  {                                        // stage episode flags [lt][4]
    int n = tc << 2;
    for (int idx = tid; idx < n; idx += 1024) {
      int s = idx & 3, llt = idx >> 2;
      flgl[idx] = ep[(size_t)(s0 + s) * 512 + t0 + llt];
    }
  }

  i32x4 wq[4][4];                          // persistent W_hh fragments (64 VGPR)
  #pragma unroll
  for (int g = 0; g < 4; ++g)
    #pragma unroll
    for (int kk = 0; kk < 4; ++kk)
      wq[g][kk] = *(const i32x4*)(Wq + (size_t)(g * 256 + j) * 256 + kk * 64 + (lq << 4));
  float dsc[4];
  #pragma unroll
  for (int g = 0; g < 4; ++g) {
    float sgn = (g == 2) ? L2E2 : -L2E;
    dsc[g] = sgn * wsc[g * 256 + j] * (1.f / 127.f);
  }

  float cst;                               // c state: seq s0+lq, col j
  {
    const float* csrc = (t0 == 0) ? c0 : cstate;
    cst = csrc[(size_t)(s0 + lq) * 256 + j];
  }

  const size_t xoff = ((size_t)(s0 + lq) * 256 + j) * 4;
  u16x4 xqA, xqB;
  xqA = *(const u16x4*)(xp + xoff);        // lt = 0
  __syncthreads();                          // staging barrier (full, once)

  const int aoff = (lc & 3) * 272 + (lq << 4);  // A-frag: row lc -> seq lc&3 (bcast)
  const i32x4 zero4 = {0, 0, 0, 0};
  // flag registers: current step (A) preloaded; next step (B) fetched pre-barrier.
  float faA = flgl[lc & 3], frA = flgl[lq];
  float faB, frB;

#define STEP(HR, HWR, XC, XN, FAc, FRc, FAn, FRn, LT)                          \
  {                                                                            \
    const int lt_ = (LT);                                                      \
    if (lt_ + 1 < tc)                    /* early prefetch: next xp -> XN */   \
      XN = *(const u16x4*)(xp + (size_t)(lt_ + 1) * 262144 + xoff);            \
    i32x4 racc[4];                                                             \
    const signed char* hbase = &(HR)[0][0];                                    \
    {                                                                          \
      i32x4 a = *(const i32x4*)(hbase + aoff);                                 \
      i32x4 am = (FAc != 0.f) ? zero4 : a;                                     \
      _Pragma("unroll")                                                        \
      for (int g = 0; g < 4; ++g)                                              \
        racc[g] = __builtin_amdgcn_mfma_i32_16x16x64_i8(am, wq[g][0], zero4, 0, 0, 0); \
    }                                                                          \
    _Pragma("unroll")                                                          \
    for (int kk = 1; kk < 4; ++kk) {                                           \
      i32x4 a = *(const i32x4*)(hbase + aoff + kk * 64);                       \
      i32x4 am = (FAc != 0.f) ? zero4 : a;                                     \
      _Pragma("unroll")                                                        \
      for (int g = 0; g < 4; ++g)                                              \
        racc[g] = __builtin_amdgcn_mfma_i32_16x16x64_i8(am, wq[g][kk], racc[g], 0, 0, 0); \
    }                                                                          \
    /* select seq lq from C rows (seq == reg): 3 static cndmasks per gamma */  \
    int r01_0 = (lq & 1) ? racc[0][1] : racc[0][0];                            \
    int r23_0 = (lq & 1) ? racc[0][3] : racc[0][2];                            \
    int g0 = (lq & 2) ? r23_0 : r01_0;                                         \
    int r01_1 = (lq & 1) ? racc[1][1] : racc[1][0];                            \
    int r23_1 = (lq & 1) ? racc[1][3] : racc[1][2];                            \
    int g1 = (lq & 2) ? r23_1 : r01_1;                                         \
    int r01_2 = (lq & 1) ? racc[2][1] : racc[2][0];                            \
    int r23_2 = (lq & 1) ? racc[2][3] : racc[2][2];                            \
    int g2 = (lq & 2) ? r23_2 : r01_2;                                         \
    int r01_3 = (lq & 1) ? racc[3][1] : racc[3][0];                            \
    int r23_3 = (lq & 1) ? racc[3][3] : racc[3][2];                            \
    int g3 = (lq & 2) ? r23_3 : r01_3;                                         \
    u16x4 xv = XC;                                                             \
    float xi = fmaf((float)g0, dsc[0], bf2f(xv.x));                            \
    float xf = fmaf((float)g1, dsc[1], bf2f(xv.y));                            \
    float xg = fmaf((float)g2, dsc[2], bf2f(xv.z));                            \
    float xo = fmaf((float)g3, dsc[3], bf2f(xv.w));                            \
    float si = frcp(1.f + fexp2(xi));                                          \
    float sf = frcp(1.f + fexp2(xf));                                          \
    float so = frcp(1.f + fexp2(xo));                                          \
    float tg = fmaf(-2.f, frcp(1.f + fexp2(xg)), 1.f);                         \
    float cp = (FRc != 0.f) ? 0.f : cst;                                       \
    float cn = fmaf(sf, cp, si * tg);                                          \
    cst = cn;                                                                  \
    float th = fmaf(-2.f, frcp(1.f + fexp2(L2E2 * cn)), 1.f);                  \
    float hn = so * th;                                                        \
    float qf = fmaf(hn, 127.f, MAGIC);   /* RNE int8 in low byte (== rintf) */ \
    signed char q8 = (signed char)(__float_as_uint(qf) & 255u);                \
    (&(HWR)[0][0])[lq * 272 + j] = q8;                                         \
    hbuf[((size_t)lt_ * 256 + s0 + lq) * 256 + j] = q8;                        \
    if (lt_ + 1 < tc) {                  /* next-step flags -> regs (LDS     */ \
      FAn = flgl[(lt_ + 1) * 4 + (lc & 3)];  /* immutable after staging)     */ \
      FRn = flgl[(lt_ + 1) * 4 + lq];                                          \
    }                                                                          \
    if (lt_ == tc - 1) {                                                       \
      int sq = s0 + lq;                                                        \
      hstate[(size_t)sq * 256 + j] = hn;                                       \
      cstate[(size_t)sq * 256 + j] = cn;                                       \
      if (last) {                                                              \
        out[4325376 + (size_t)sq * 256 + j] = hn;                              \
        out[4390912 + (size_t)sq * 256 + j] = cn;                              \
      }                                                                        \
    }                                                                          \
    asm volatile("s_waitcnt lgkmcnt(0)\n\ts_barrier" ::: "memory");            \
  }

  for (int lt = 0; lt < tc; lt += 2) {     // tc even
    STEP(Hl[0], Hl[1], xqA, xqB, faA, frA, faB, frB, lt);
    STEP(Hl[1], Hl[0], xqB, xqA, faB, frB, faA, frA, lt + 1);
  }
#undef STEP
}

// --- K3 body (512 active of 1024): heads GEMM from int8 hbuf [lt][s][j].
__device__ __forceinline__ void k3_body(int gk,
                                        const signed char* __restrict__ hbuf,
                                        const signed char* __restrict__ Wlq,
                                        const float* __restrict__ lsc,
                                        const float* __restrict__ blog,
                                        const float* __restrict__ bval,
                                        float* __restrict__ out,
                                        int t0, int tc, int tcsh) {
  if (threadIdx.x >= 512) return;
  const int w = threadIdx.x >> 6, l = threadIdx.x & 63;
  const int lc = l & 15, lq = l >> 4;
  const int tk = gk * 8 + w;                    // 0 .. 16*tc-1
  const int pg = tk >> tcsh, lt = tk & (tc - 1);
  const int t = t0 + lt;
  const i32x4 zero4 = {0, 0, 0, 0};

  i32x4 dacc[3] = {zero4, zero4, zero4};
  #pragma unroll
  for (int kk = 0; kk < 4; ++kk) {
    i32x4 a = *(const i32x4*)(hbuf + ((size_t)lt * 256 + (pg << 4) + lc) * 256
                              + kk * 64 + (lq << 4));
    #pragma unroll
    for (int n = 0; n < 3; ++n) {
      int row = n * 16 + lc;
      i32x4 bf = (row < 33) ? *(const i32x4*)(Wlq + (size_t)row * 256 + kk * 64 + (lq << 4))
                            : zero4;
      dacc[n] = __builtin_amdgcn_mfma_i32_16x16x64_i8(a, bf, dacc[n], 0, 0, 0);
    }
  }
  #pragma unroll
  for (int n = 0; n < 2; ++n) {
    float dsn = lsc[n * 16 + lc] * (1.f / 127.f);
    float lbn = blog[n * 16 + lc];
    #pragma unroll
    for (int r = 0; r < 4; ++r) {
      int sg = (pg << 4) + lq * 4 + r;
      out[((size_t)sg * 512 + t) * 32 + n * 16 + lc] = fmaf((float)dacc[n][r], dsn, lbn);
    }
  }
  if (lc == 0) {
    float ds2 = lsc[32] * (1.f / 127.f);
    float b2 = bval[0];
    #pragma unroll
    for (int r = 0; r < 4; ++r) {
      int sg = (pg << 4) + lq * 4 + r;
      out[4194304 + (size_t)sg * 512 + t] = fmaf((float)dacc[2][r], ds2, b2);
    }
  }
}

// ================================================================ MEGA
__launch_bounds__(1024, 1)
__global__ void mega(int nk2, int t0_2, const unsigned short* xp2, signed char* hb2,
                     int nk1, int t0_1, unsigned short* xp1,
                     int nk3, int t0_3, const signed char* hb3,
                     const float* feat, const float* Wih,
                     const float* bih, const float* bhh,
                     const signed char* Wq, const float* wsc,
                     const signed char* Wlq, const float* lsc,
                     const float* ep, const float* h0, const float* c0,
                     const float* blog, const float* bval,
                     float* hstate, float* cstate, float* out,
                     int tc, int tcsh) {
  __shared__ __align__(16) char smem[35840];
  int bid = (int)blockIdx.x;
  if (bid < nk2) {
    k2_body(bid, smem, xp2, Wq, wsc, ep, h0, c0, hstate, cstate, hb2, out, t0_2, tc);
  } else if (bid < nk2 + nk1) {
    k1_body(bid - nk2, smem, feat, Wih, bih, bhh, xp1, t0_1);
  } else {
    k3_body(bid - nk2 - nk1, hb3, Wlq, lsc, blog, bval, out, t0_3, tc, tcsh);
  }
}

// ---------------------------------------------------------------- launcher
extern "C" void kernel_launch(void* const* d_in, const int* in_sizes, int n_in,
                              void* d_out, int out_size, void* d_ws, size_t ws_size,
                              hipStream_t stream) {
  const float* feat = (const float*)d_in[0];
  const float* ep   = (const float*)d_in[1];
  const float* h0   = (const float*)d_in[2];
  const float* c0   = (const float*)d_in[3];
  const float* Wih  = (const float*)d_in[4];
  const float* Whh  = (const float*)d_in[5];
  const float* bih  = (const float*)d_in[6];
  const float* bhh  = (const float*)d_in[7];
  const float* Wlog = (const float*)d_in[8];
  const float* blog = (const float*)d_in[9];
  const float* Wval = (const float*)d_in[10];
  const float* bval = (const float*)d_in[11];
  float* out = (float*)d_out;
  char* ws = (char*)d_ws;
  signed char* Wq     = (signed char*)(ws + 0);        // 262144
  float*       wsc    = (float*)      (ws + 262144);   // 4096
  signed char* Wlq    = (signed char*)(ws + 266240);   // 8448
  float*       lsc    = (float*)      (ws + 274688);   // 132
  float*       hstate = (float*)      (ws + 275456);   // 262144
  float*       cstate = (float*)      (ws + 537600);   // 262144 (ends 799744)

  int Tc = 128;
  while (Tc > 16 && (size_t)1048576 + (size_t)Tc * 1179648 > ws_size) Tc >>= 1;
  int tcsh = 31 - __builtin_clz(Tc);
  int nc = 512 / Tc;
  size_t xpsz = (size_t)Tc * 524288, hbsz = (size_t)Tc * 65536;
  unsigned short* xpb[2] = { (unsigned short*)(ws + 1048576),
                             (unsigned short*)(ws + 1048576 + xpsz) };
  signed char*    hbb[2] = { (signed char*)(ws + 1048576 + 2 * xpsz),
                             (signed char*)(ws + 1048576 + 2 * xpsz + hbsz) };
  const int NK1 = Tc * 16;   // k1 tiles: (Tc*256/128 m-tiles) * 8 bn
  const int NK3 = Tc * 2;    // k3: 16*Tc wave-tasks / 8 waves
  const int NK2 = 64;

  hipLaunchKernelGGL(k0_quant, dim3(1057), dim3(64), 0, stream,
                     Whh, Wlog, Wval, Wq, wsc, Wlq, lsc);
  // lead-in: k1 for chunk 0
  hipLaunchKernelGGL(mega, dim3(NK1), dim3(1024), 0, stream,
                     0, 0, xpb[0], hbb[0],
                     NK1, 0, xpb[0],
                     0, 0, hbb[0],
                     feat, Wih, bih, bhh, Wq, wsc, Wlq, lsc, ep, h0, c0,
                     blog, bval, hstate, cstate, out, Tc, tcsh);
  for (int j = 0; j < nc; ++j) {
    int nk1 = (j + 1 < nc) ? NK1 : 0;
    int nk3 = (j >= 1) ? NK3 : 0;
    hipLaunchKernelGGL(mega, dim3(NK2 + nk1 + nk3), dim3(1024), 0, stream,
                       NK2, j * Tc, xpb[j & 1], hbb[j & 1],
                       nk1, (j + 1) * Tc, xpb[(j + 1) & 1],
                       nk3, (j - 1) * Tc, hbb[(j + 1) & 1],   // (j-1)&1 == (j+1)&1
                       feat, Wih, bih, bhh, Wq, wsc, Wlq, lsc, ep, h0, c0,
                       blog, bval, hstate, cstate, out, Tc, tcsh);
  }
  // tail: k3 for last chunk
  hipLaunchKernelGGL(mega, dim3(NK3), dim3(1024), 0, stream,
                     0, 0, xpb[0], hbb[0],
                     0, 0, xpb[0],
                     NK3, (nc - 1) * Tc, hbb[(nc - 1) & 1],
                     feat, Wih, bih, bhh, Wq, wsc, Wlq, lsc, ep, h0, c0,
                     blog, bval, hstate, cstate, out, Tc, tcsh);
}

// Round 14
// 519.521 us; speedup vs baseline: 1.1803x; 1.0565x over previous
//
#include <hip/hip_runtime.h>
#include <hip/hip_bf16.h>

// ACLSTM on MI355X — persistent-RNN, time-chunked + software-pipelined.
// R14: k2 serial-tail restructure (k1/k3/pipeline untouched from R13-PASS):
//      (1) gamma-outer MFMA order: racc[0] completes after 4 MFMAs -> gate-i
//          chain overlaps remaining MFMA issue (kk order per racc unchanged
//          -> bitwise-identical accumulation);
//      (2) write-time h-masking: Hl gets (flag[t+1] ? 0 : q8); removes all 16
//          read-side cndmasks + flag dep from the barrier->ds_read->MFMA head.
//          hbuf keeps unmasked q8; chunk staging masks by flag[t0].
//      absmax canary: must remain exactly 0.01074219.

typedef float f32x4 __attribute__((ext_vector_type(4)));
typedef int   i32x4 __attribute__((ext_vector_type(4)));
typedef short s16x8 __attribute__((ext_vector_type(8)));
typedef short s16x4 __attribute__((ext_vector_type(4)));
typedef unsigned short u16x4 __attribute__((ext_vector_type(4)));

#define L2E   1.44269504088896340736f
#define L2E2  2.88539008177792681472f
#define MAGIC 12582912.f                      // 1.5 * 2^23

__device__ __forceinline__ float fexp2(float x) {
#if __has_builtin(__builtin_amdgcn_exp2f)
  return __builtin_amdgcn_exp2f(x);
#else
  float r; asm("v_exp_f32 %0, %1" : "=v"(r) : "v"(x)); return r;
#endif
}
__device__ __forceinline__ float frcp(float x) { return __builtin_amdgcn_rcpf(x); }
__device__ __forceinline__ float bf2f(unsigned short u) {
  return __uint_as_float(((unsigned)u) << 16);
}
__device__ __forceinline__ unsigned short f2bf(float f) {   // RNE f32->bf16
  unsigned int b = __float_as_uint(f);
  return (unsigned short)((b + 0x7FFFu + ((b >> 16) & 1u)) >> 16);
}

// ---------------------------------------------------------------- K0: quant
__global__ void k0_quant(const float* __restrict__ Whh,
                         const float* __restrict__ Wlog,
                         const float* __restrict__ Wval,
                         signed char* __restrict__ Wq, float* __restrict__ wsc,
                         signed char* __restrict__ Wlq, float* __restrict__ lsc) {
  int r = blockIdx.x, l = threadIdx.x;   // 1057 rows, 64 lanes
  const float* src; signed char* dst; float* sd;
  if (r < 1024) { src = Whh + (size_t)r * 256; dst = Wq + (size_t)r * 256; sd = wsc + r; }
  else {
    int hr = r - 1024;
    src = (hr < 32) ? (Wlog + (size_t)hr * 256) : Wval;
    dst = Wlq + (size_t)hr * 256; sd = lsc + hr;
  }
  f32x4 v = *(const f32x4*)(src + l * 4);
  float m = fmaxf(fmaxf(fabsf(v.x), fabsf(v.y)), fmaxf(fabsf(v.z), fabsf(v.w)));
  #pragma unroll
  for (int off = 32; off; off >>= 1) m = fmaxf(m, __shfl_xor(m, off));
  float inv = (m > 0.f) ? (127.f / m) : 0.f;
  int q0 = (int)rintf(v.x * inv), q1 = (int)rintf(v.y * inv);
  int q2 = (int)rintf(v.z * inv), q3 = (int)rintf(v.w * inv);
  unsigned int pk = (q0 & 255) | ((q1 & 255) << 8) | ((q2 & 255) << 16) | ((q3 & 255) << 24);
  *(unsigned int*)(dst + l * 4) = pk;
  if (l == 0) *sd = m * (1.f / 127.f);
}

// ================================================================ bodies
// --- K1 body (512 active of 1024 threads): M=128 x N=128(=32j x 4gm).
__device__ __forceinline__ void k1_body(int gk, char* smem,
                                        const float* __restrict__ feat,
                                        const float* __restrict__ Wih,
                                        const float* __restrict__ bih,
                                        const float* __restrict__ bhh,
                                        unsigned short* __restrict__ xp, int t0) {
  short (*Bl)[136] = (short (*)[136])smem;                  // 128x136 = 34816 B
  float* bias = (float*)(smem + 34816);                     // 512 B
  const int tid = threadIdx.x;
  const int bm = gk >> 3, bn = gk & 7;
  const int m0 = bm << 7, j0 = bn << 5;
  const int tg = t0 + (bm >> 1), sbase = (bm & 1) << 7;     // 128 | 256
  s16x8 a[4];
  if (tid < 512) {
    #pragma unroll
    for (int it = 0; it < 8; ++it) {             // B: 128 g-rows x 128 k
      int idx = it * 512 + tid;
      int rr = idx >> 5, c4 = (idx & 31) << 2;
      int g = ((rr & 3) << 8) + j0 + (rr >> 2);
      f32x4 v = *(const f32x4*)(Wih + (size_t)g * 128 + c4);
      s16x4 pk = { (short)f2bf(v.x), (short)f2bf(v.y), (short)f2bf(v.z), (short)f2bf(v.w) };
      *(s16x4*)&Bl[rr][c4] = pk;
    }
    if (tid < 128) {
      int g = ((tid & 3) << 8) + j0 + (tid >> 2);
      bias[tid] = bih[g] + bhh[g];
    }
    const int w = tid >> 6, l = tid & 63;
    const int lr = l & 15, lk8 = (l >> 4) << 3;
    const float* fp = feat + ((size_t)(sbase + (w << 4) + lr) * 512 + tg) * 128 + lk8;
    #pragma unroll
    for (int kk = 0; kk < 4; ++kk) {
      f32x4 v0 = *(const f32x4*)(fp + kk * 32);
      f32x4 v1 = *(const f32x4*)(fp + kk * 32 + 4);
      s16x8 pk = { (short)f2bf(v0.x), (short)f2bf(v0.y), (short)f2bf(v0.z), (short)f2bf(v0.w),
                   (short)f2bf(v1.x), (short)f2bf(v1.y), (short)f2bf(v1.z), (short)f2bf(v1.w) };
      a[kk] = pk;
    }
  }
  __syncthreads();
  if (tid >= 512) return;
  const int w = tid >> 6, l = tid & 63;
  const int lr = l & 15, lk8 = (l >> 4) << 3;
  f32x4 z = {0.f, 0.f, 0.f, 0.f};
  f32x4 acc[8];
  #pragma unroll
  for (int nt = 0; nt < 8; ++nt) acc[nt] = z;
  #pragma unroll
  for (int kk = 0; kk < 4; ++kk) {
    #pragma unroll
    for (int nt = 0; nt < 8; ++nt) {
      s16x8 bb = *(const s16x8*)&Bl[nt * 16 + lr][kk * 32 + lk8];
      acc[nt] = __builtin_amdgcn_mfma_f32_16x16x32_bf16(a[kk], bb, acc[nt], 0, 0, 0);
    }
  }
  #pragma unroll
  for (int nt = 0; nt < 8; ++nt) {
    #pragma unroll
    for (int r = 0; r < 4; ++r) {
      int m = m0 + (w << 4) + (l >> 4) * 4 + r;   // chunk-local
      int c = nt * 16 + lr;
      float gsc = ((c & 3) == 2) ? L2E2 : -L2E;
      float val = (acc[nt][r] + bias[c]) * gsc;
      xp[(size_t)m * 1024 + (j0 << 2) + c] = f2bf(val);
    }
  }
}

// --- K2 body: 64 blocks x 4 seqs, 1024 threads, 1 cell/lane.
__device__ __forceinline__ void k2_body(int bid, char* smem,
                                        const unsigned short* __restrict__ xp,
                                        const signed char* __restrict__ Wq,
                                        const float* __restrict__ wsc,
                                        const float* __restrict__ ep,
                                        const float* __restrict__ h0,
                                        const float* __restrict__ c0,
                                        float* __restrict__ hstate,
                                        float* __restrict__ cstate,
                                        signed char* __restrict__ hbuf,
                                        float* __restrict__ out, int t0, int tc) {
  __builtin_amdgcn_s_setprio(3);
  signed char (*Hl)[4][272] = (signed char (*)[4][272])smem;  // 2x4x272 = 2176
  float* flgl = (float*)(smem + 2176);     // [lt][4] flags, tc*16 B
  const int tid = threadIdx.x;             // 0..1023
  const int w = tid >> 6, l = tid & 63;    // w: 0..15
  const int lc = l & 15, lq = l >> 4;
  const int j = (w << 4) + lc;             // lane's h-column, 0..255
  const int s0 = bid << 2;
  const bool last = (t0 + tc == 512);

  {                                        // stage h rows 0..3 (int8, MASKED by flag[t0])
    const float* hsrc = (t0 == 0) ? h0 : hstate;
    int s = tid >> 8, jj = tid & 255;
    float v = hsrc[(size_t)(s0 + s) * 256 + jj];
    float fl = ep[(size_t)(s0 + s) * 512 + t0];
    float q = rintf(fminf(fmaxf(v * 127.f, -127.f), 127.f));
    Hl[0][s][jj] = (fl != 0.f) ? (signed char)0 : (signed char)(int)q;
  }
  {                                        // stage episode flags [lt][4]
    int n = tc << 2;
    for (int idx = tid; idx < n; idx += 1024) {
      int s = idx & 3, llt = idx >> 2;
      flgl[idx] = ep[(size_t)(s0 + s) * 512 + t0 + llt];
    }
  }

  i32x4 wq[4][4];                          // persistent W_hh fragments (64 VGPR)
  #pragma unroll
  for (int g = 0; g < 4; ++g)
    #pragma unroll
    for (int kk = 0; kk < 4; ++kk)
      wq[g][kk] = *(const i32x4*)(Wq + (size_t)(g * 256 + j) * 256 + kk * 64 + (lq << 4));
  float dsc[4];
  #pragma unroll
  for (int g = 0; g < 4; ++g) {
    float sgn = (g == 2) ? L2E2 : -L2E;
    dsc[g] = sgn * wsc[g * 256 + j] * (1.f / 127.f);
  }

  float cst;                               // c state: seq s0+lq, col j
  {
    const float* csrc = (t0 == 0) ? c0 : cstate;
    cst = csrc[(size_t)(s0 + lq) * 256 + j];
  }

  const size_t xoff = ((size_t)(s0 + lq) * 256 + j) * 4;
  u16x4 xqA, xqB;
  xqA = *(const u16x4*)(xp + xoff);        // lt = 0
  __syncthreads();                          // staging barrier (full, once)

  const int aoff = (lc & 3) * 272 + (lq << 4);  // A-frag: row lc -> seq lc&3 (bcast)
  const i32x4 zero4 = {0, 0, 0, 0};
  float frA = flgl[lq], frB = 0.f;         // c-mask, current step

#define STEP(HR, HWR, XC, XN, FRc, FRn, LT)                                    \
  {                                                                            \
    const int lt_ = (LT);                                                      \
    if (lt_ + 1 < tc)                    /* early prefetch: next xp -> XN */   \
      XN = *(const u16x4*)(xp + (size_t)(lt_ + 1) * 262144 + xoff);            \
    float frn = (lt_ + 1 < tc) ? flgl[(lt_ + 1) * 4 + lq] : 0.f;               \
    const signed char* hbase = &(HR)[0][0];                                    \
    i32x4 a0 = *(const i32x4*)(hbase + aoff);                                  \
    i32x4 a1 = *(const i32x4*)(hbase + aoff + 64);                             \
    i32x4 a2 = *(const i32x4*)(hbase + aoff + 128);                            \
    i32x4 a3 = *(const i32x4*)(hbase + aoff + 192);                            \
    u16x4 xv = XC;                                                             \
    /* gamma-outer: racc[g] completes early -> gate chain overlaps MFMAs */    \
    i32x4 rc0 = __builtin_amdgcn_mfma_i32_16x16x64_i8(a0, wq[0][0], zero4, 0, 0, 0); \
    rc0 = __builtin_amdgcn_mfma_i32_16x16x64_i8(a1, wq[0][1], rc0, 0, 0, 0);   \
    rc0 = __builtin_amdgcn_mfma_i32_16x16x64_i8(a2, wq[0][2], rc0, 0, 0, 0);   \
    rc0 = __builtin_amdgcn_mfma_i32_16x16x64_i8(a3, wq[0][3], rc0, 0, 0, 0);   \
    int s01_0 = (lq & 1) ? rc0[1] : rc0[0];                                    \
    int s23_0 = (lq & 1) ? rc0[3] : rc0[2];                                    \
    int g0 = (lq & 2) ? s23_0 : s01_0;                                         \
    float xi = fmaf((float)g0, dsc[0], bf2f(xv.x));                            \
    float si = frcp(1.f + fexp2(xi));                                          \
    i32x4 rc1 = __builtin_amdgcn_mfma_i32_16x16x64_i8(a0, wq[1][0], zero4, 0, 0, 0); \
    rc1 = __builtin_amdgcn_mfma_i32_16x16x64_i8(a1, wq[1][1], rc1, 0, 0, 0);   \
    rc1 = __builtin_amdgcn_mfma_i32_16x16x64_i8(a2, wq[1][2], rc1, 0, 0, 0);   \
    rc1 = __builtin_amdgcn_mfma_i32_16x16x64_i8(a3, wq[1][3], rc1, 0, 0, 0);   \
    int s01_1 = (lq & 1) ? rc1[1] : rc1[0];                                    \
    int s23_1 = (lq & 1) ? rc1[3] : rc1[2];                                    \
    int g1 = (lq & 2) ? s23_1 : s01_1;                                         \
    float xf = fmaf((float)g1, dsc[1], bf2f(xv.y));                            \
    float sf = frcp(1.f + fexp2(xf));                                          \
    i32x4 rc2 = __builtin_amdgcn_mfma_i32_16x16x64_i8(a0, wq[2][0], zero4, 0, 0, 0); \
    rc2 = __builtin_amdgcn_mfma_i32_16x16x64_i8(a1, wq[2][1], rc2, 0, 0, 0);   \
    rc2 = __builtin_amdgcn_mfma_i32_16x16x64_i8(a2, wq[2][2], rc2, 0, 0, 0);   \
    rc2 = __builtin_amdgcn_mfma_i32_16x16x64_i8(a3, wq[2][3], rc2, 0, 0, 0);   \
    int s01_2 = (lq & 1) ? rc2[1] : rc2[0];                                    \
    int s23_2 = (lq & 1) ? rc2[3] : rc2[2];                                    \
    int g2 = (lq & 2) ? s23_2 : s01_2;                                         \
    float xg = fmaf((float)g2, dsc[2], bf2f(xv.z));                            \
    float tg = fmaf(-2.f, frcp(1.f + fexp2(xg)), 1.f);                         \
    i32x4 rc3 = __builtin_amdgcn_mfma_i32_16x16x64_i8(a0, wq[3][0], zero4, 0, 0, 0); \
    rc3 = __builtin_amdgcn_mfma_i32_16x16x64_i8(a1, wq[3][1], rc3, 0, 0, 0);   \
    rc3 = __builtin_amdgcn_mfma_i32_16x16x64_i8(a2, wq[3][2], rc3, 0, 0, 0);   \
    rc3 = __builtin_amdgcn_mfma_i32_16x16x64_i8(a3, wq[3][3], rc3, 0, 0, 0);   \
    int s01_3 = (lq & 1) ? rc3[1] : rc3[0];                                    \
    int s23_3 = (lq & 1) ? rc3[3] : rc3[2];                                    \
    int g3 = (lq & 2) ? s23_3 : s01_3;                                         \
    float xo = fmaf((float)g3, dsc[3], bf2f(xv.w));                            \
    float so = frcp(1.f + fexp2(xo));                                          \
    float cp = (FRc != 0.f) ? 0.f : cst;                                       \
    float cn = fmaf(sf, cp, si * tg);                                          \
    cst = cn;                                                                  \
    float th = fmaf(-2.f, frcp(1.f + fexp2(L2E2 * cn)), 1.f);                  \
    float hn = so * th;                                                        \
    float qf = fmaf(hn, 127.f, MAGIC);   /* RNE int8 in low byte */            \
    signed char q8 = (signed char)(__float_as_uint(qf) & 255u);                \
    signed char q8m = (frn != 0.f) ? (signed char)0 : q8;  /* write-masked */  \
    (&(HWR)[0][0])[lq * 272 + j] = q8m;                                        \
    hbuf[((size_t)lt_ * 256 + s0 + lq) * 256 + j] = q8;                        \
    FRn = frn;                                                                 \
    if (lt_ == tc - 1) {                                                       \
      int sq = s0 + lq;                                                        \
      hstate[(size_t)sq * 256 + j] = hn;                                       \
      cstate[(size_t)sq * 256 + j] = cn;                                       \
      if (last) {                                                              \
        out[4325376 + (size_t)sq * 256 + j] = hn;                              \
        out[4390912 + (size_t)sq * 256 + j] = cn;                              \
      }                                                                        \
    }                                                                          \
    asm volatile("s_waitcnt lgkmcnt(0)\n\ts_barrier" ::: "memory");            \
  }

  for (int lt = 0; lt < tc; lt += 2) {     // tc even
    STEP(Hl[0], Hl[1], xqA, xqB, frA, frB, lt);
    STEP(Hl[1], Hl[0], xqB, xqA, frB, frA, lt + 1);
  }
#undef STEP
}

// --- K3 body (512 active of 1024): heads GEMM from int8 hbuf [lt][s][j].
__device__ __forceinline__ void k3_body(int gk,
                                        const signed char* __restrict__ hbuf,
                                        const signed char* __restrict__ Wlq,
                                        const float* __restrict__ lsc,
                                        const float* __restrict__ blog,
                                        const float* __restrict__ bval,
                                        float* __restrict__ out,
                                        int t0, int tc, int tcsh) {
  if (threadIdx.x >= 512) return;
  const int w = threadIdx.x >> 6, l = threadIdx.x & 63;
  const int lc = l & 15, lq = l >> 4;
  const int tk = gk * 8 + w;                    // 0 .. 16*tc-1
  const int pg = tk >> tcsh, lt = tk & (tc - 1);
  const int t = t0 + lt;
  const i32x4 zero4 = {0, 0, 0, 0};

  i32x4 dacc[3] = {zero4, zero4, zero4};
  #pragma unroll
  for (int kk = 0; kk < 4; ++kk) {
    i32x4 a = *(const i32x4*)(hbuf + ((size_t)lt * 256 + (pg << 4) + lc) * 256
                              + kk * 64 + (lq << 4));
    #pragma unroll
    for (int n = 0; n < 3; ++n) {
      int row = n * 16 + lc;
      i32x4 bf = (row < 33) ? *(const i32x4*)(Wlq + (size_t)row * 256 + kk * 64 + (lq << 4))
                            : zero4;
      dacc[n] = __builtin_amdgcn_mfma_i32_16x16x64_i8(a, bf, dacc[n], 0, 0, 0);
    }
  }
  #pragma unroll
  for (int n = 0; n < 2; ++n) {
    float dsn = lsc[n * 16 + lc] * (1.f / 127.f);
    float lbn = blog[n * 16 + lc];
    #pragma unroll
    for (int r = 0; r < 4; ++r) {
      int sg = (pg << 4) + lq * 4 + r;
      out[((size_t)sg * 512 + t) * 32 + n * 16 + lc] = fmaf((float)dacc[n][r], dsn, lbn);
    }
  }
  if (lc == 0) {
    float ds2 = lsc[32] * (1.f / 127.f);
    float b2 = bval[0];
    #pragma unroll
    for (int r = 0; r < 4; ++r) {
      int sg = (pg << 4) + lq * 4 + r;
      out[4194304 + (size_t)sg * 512 + t] = fmaf((float)dacc[2][r], ds2, b2);
    }
  }
}

// ================================================================ MEGA
__launch_bounds__(1024, 1)
__global__ void mega(int nk2, int t0_2, const unsigned short* xp2, signed char* hb2,
                     int nk1, int t0_1, unsigned short* xp1,
                     int nk3, int t0_3, const signed char* hb3,
                     const float* feat, const float* Wih,
                     const float* bih, const float* bhh,
                     const signed char* Wq, const float* wsc,
                     const signed char* Wlq, const float* lsc,
                     const float* ep, const float* h0, const float* c0,
                     const float* blog, const float* bval,
                     float* hstate, float* cstate, float* out,
                     int tc, int tcsh) {
  __shared__ __align__(16) char smem[35840];
  int bid = (int)blockIdx.x;
  if (bid < nk2) {
    k2_body(bid, smem, xp2, Wq, wsc, ep, h0, c0, hstate, cstate, hb2, out, t0_2, tc);
  } else if (bid < nk2 + nk1) {
    k1_body(bid - nk2, smem, feat, Wih, bih, bhh, xp1, t0_1);
  } else {
    k3_body(bid - nk2 - nk1, hb3, Wlq, lsc, blog, bval, out, t0_3, tc, tcsh);
  }
}

// ---------------------------------------------------------------- launcher
extern "C" void kernel_launch(void* const* d_in, const int* in_sizes, int n_in,
                              void* d_out, int out_size, void* d_ws, size_t ws_size,
                              hipStream_t stream) {
  const float* feat = (const float*)d_in[0];
  const float* ep   = (const float*)d_in[1];
  const float* h0   = (const float*)d_in[2];
  const float* c0   = (const float*)d_in[3];
  const float* Wih  = (const float*)d_in[4];
  const float* Whh  = (const float*)d_in[5];
  const float* bih  = (const float*)d_in[6];
  const float* bhh  = (const float*)d_in[7];
  const float* Wlog = (const float*)d_in[8];
  const float* blog = (const float*)d_in[9];
  const float* Wval = (const float*)d_in[10];
  const float* bval = (const float*)d_in[11];
  float* out = (float*)d_out;
  char* ws = (char*)d_ws;
  signed char* Wq     = (signed char*)(ws + 0);        // 262144
  float*       wsc    = (float*)      (ws + 262144);   // 4096
  signed char* Wlq    = (signed char*)(ws + 266240);   // 8448
  float*       lsc    = (float*)      (ws + 274688);   // 132
  float*       hstate = (float*)      (ws + 275456);   // 262144
  float*       cstate = (float*)      (ws + 537600);   // 262144 (ends 799744)

  int Tc = 128;
  while (Tc > 16 && (size_t)1048576 + (size_t)Tc * 1179648 > ws_size) Tc >>= 1;
  int tcsh = 31 - __builtin_clz(Tc);
  int nc = 512 / Tc;
  size_t xpsz = (size_t)Tc * 524288, hbsz = (size_t)Tc * 65536;
  unsigned short* xpb[2] = { (unsigned short*)(ws + 1048576),
                             (unsigned short*)(ws + 1048576 + xpsz) };
  signed char*    hbb[2] = { (signed char*)(ws + 1048576 + 2 * xpsz),
                             (signed char*)(ws + 1048576 + 2 * xpsz + hbsz) };
  const int NK1 = Tc * 16;   // k1 tiles: (Tc*256/128 m-tiles) * 8 bn
  const int NK3 = Tc * 2;    // k3: 16*Tc wave-tasks / 8 waves
  const int NK2 = 64;

  hipLaunchKernelGGL(k0_quant, dim3(1057), dim3(64), 0, stream,
                     Whh, Wlog, Wval, Wq, wsc, Wlq, lsc);
  // lead-in: k1 for chunk 0
  hipLaunchKernelGGL(mega, dim3(NK1), dim3(1024), 0, stream,
                     0, 0, xpb[0], hbb[0],
                     NK1, 0, xpb[0],
                     0, 0, hbb[0],
                     feat, Wih, bih, bhh, Wq, wsc, Wlq, lsc, ep, h0, c0,
                     blog, bval, hstate, cstate, out, Tc, tcsh);
  for (int j = 0; j < nc; ++j) {
    int nk1 = (j + 1 < nc) ? NK1 : 0;
    int nk3 = (j >= 1) ? NK3 : 0;
    hipLaunchKernelGGL(mega, dim3(NK2 + nk1 + nk3), dim3(1024), 0, stream,
                       NK2, j * Tc, xpb[j & 1], hbb[j & 1],
                       nk1, (j + 1) * Tc, xpb[(j + 1) & 1],
                       nk3, (j - 1) * Tc, hbb[(j + 1) & 1],   // (j-1)&1 == (j+1)&1
                       feat, Wih, bih, bhh, Wq, wsc, Wlq, lsc, ep, h0, c0,
                       blog, bval, hstate, cstate, out, Tc, tcsh);
  }
  // tail: k3 for last chunk
  hipLaunchKernelGGL(mega, dim3(NK3), dim3(1024), 0, stream,
                     0, 0, xpb[0], hbb[0],
                     0, 0, xpb[0],
                     NK3, (nc - 1) * Tc, hbb[(nc - 1) & 1],
                     feat, Wih, bih, bhh, Wq, wsc, Wlq, lsc, ep, h0, c0,
                     blog, bval, hstate, cstate, out, Tc, tcsh);
}